// Round 16
// baseline (440.397 us; speedup 1.0000x reference)
//
#include <hip/hip_runtime.h>
#include <cmath>

#define D_IN 256
#define H_DIM 128
#define NUM_GRAPHS 1024
#define CHUNK 16
#define MAXSEG 2
#define NPERS 1024     // persistent blocks (4 per CU)
#define REC_F 768      // floats per record: ewsum[256], ssum[256], mx[256]

typedef __attribute__((ext_vector_type(8))) __bf16 bf16x8;
typedef __attribute__((ext_vector_type(4))) float f32x4;

// async global->LDS DMA, 16B per lane: dest = wave-uniform base + lane*16.
__device__ inline void load_lds_16(const void* g, void* l) {
    __builtin_amdgcn_global_load_lds(
        (const __attribute__((address_space(1))) void*)g,
        (__attribute__((address_space(3))) void*)l, 16, 0, 0);
}

// lgkm-only barrier: does NOT drain vmcnt -> in-flight DMA survives.
__device__ inline void bar_lds() {
    asm volatile("s_waitcnt lgkmcnt(0)" ::: "memory");
    __builtin_amdgcn_s_barrier();
    asm volatile("" ::: "memory");
}

__device__ inline int lower_bound_i(const int* __restrict__ arr, int n, int val) {
    int lo = 0, hi = n;
    while (lo < hi) {
        int mid = (lo + hi) >> 1;
        if (arr[mid] < val) lo = mid + 1; else hi = mid;
    }
    return lo;
}

// ---------------------------------------------------------------------------
// prep: blocks 0-15 pack W1 to MFMA B-frag order; blocks 16-20: per-graph
// bounds via binary search on sorted batch.
// B-frag: lane l holds B[k][n], n = nt*16+(l&15), k = ks*32+(l>>4)*8+i.
// ---------------------------------------------------------------------------
__global__ __launch_bounds__(256) void prep_kernel(
    const float* __restrict__ W1, const int* __restrict__ batch, int N,
    ushort* __restrict__ packed, int* __restrict__ bounds) {
    int b = blockIdx.x;
    if (b < 16) {
        int tid = b * 256 + threadIdx.x;
        int nt = tid >> 9;
        int ks = (tid >> 6) & 7;
        int l = tid & 63;
        int col = nt * 16 + (l & 15);
        int kbase = ks * 32 + ((l >> 4) & 3) * 8;
#pragma unroll
        for (int i = 0; i < 8; ++i) {
            float v = W1[(size_t)(kbase + i) * H_DIM + col];
            __bf16 h = (__bf16)v;
            packed[(size_t)tid * 8 + i] = __builtin_bit_cast(unsigned short, h);
        }
    } else {
        int i = (b - 16) * 256 + threadIdx.x;
        if (i <= NUM_GRAPHS) bounds[i] = lower_bound_i(batch, N, i);
    }
}

// ---------------------------------------------------------------------------
// Persistent fused kernel: 1024 blocks x 256 threads (4 blocks/CU, one
// generation). Each block owns ~31 consecutive 16-row chunks. W1 slice in
// regs once (nt-split: wave w owns H-cols [w*32,+32)). x staged by
// global_load_lds DMA into DOUBLE-BUFFERED LDS (2 x 16 KB f32, source-
// swizzled): the chunk-boundary __syncthreads drains only DMA(t) (which had
// all of chunk t-1's compute to fly); DMA(t+1) is issued immediately after
// and stays in flight across the lgkm-only mid barrier.
// ---------------------------------------------------------------------------
__global__ __launch_bounds__(256, 4) void fused_kernel(
    const float* __restrict__ x, const ushort* __restrict__ w1p,
    const float* __restrict__ b1, const float* __restrict__ W2,
    const float* __restrict__ b2, const int* __restrict__ batch,
    float* __restrict__ recs, float* __restrict__ zpart, int N, int NB, int K) {
    int tid = threadIdx.x;
    int l = tid & 63;
    int w = tid >> 6;
    int r16 = l & 15;
    int kg = l >> 4;
    int blk = blockIdx.x;
    int c0 = blk * K;
    if (c0 >= NB) {
        if (tid == 0) zpart[blk] = 0.f;
        return;
    }
    int cEnd = min(c0 + K, NB);

    __shared__ float sxf[2][CHUNK * D_IN];  // 2 x 16 KB f32 (source-swizzled)
    __shared__ float pscore[4][CHUNK];      // [wave][row]
    __shared__ int seglist[2][MAXSEG + 1];  // parity-buffered
    __shared__ int snseg[2];

    // ---- per-block constants (ONCE): W1 slice + epilogue weights ----
    bf16x8 breg0[8], breg1[8];
#pragma unroll
    for (int ks = 0; ks < 8; ++ks) {
        breg0[ks] = *(const bf16x8*)(w1p + ((size_t)((w * 2) * 8 + ks) * 64 + l) * 8);
        breg1[ks] = *(const bf16x8*)(w1p + ((size_t)((w * 2 + 1) * 8 + ks) * 64 + l) * 8);
    }
    float w2v[2], b1v[2];
#pragma unroll
    for (int q = 0; q < 2; ++q) {
        int c = (w * 2 + q) * 16 + r16;
        w2v[q] = W2[c];
        b1v[q] = b1[c];
    }
    float bb = b2[0];

    // pool decomposition: wave w cols [w*64,+64); cg=l&15 (4 cols), rg=l>>4
    int cg = l & 15;
    int rg = l >> 4;
    unsigned cbyte = (unsigned)(w * 256 + cg * 16);

    float zacc = 0.f;

    // ---- prologue: DMA chunk c0 -> buf0; wave0 batch(c0) -> regs ----
    {
        long long base = (long long)c0 * CHUNK;
#pragma unroll
        for (int k = 0; k < 4; ++k) {
            int row = k * 4 + w;
            long long grow = base + row;
            if (grow >= N) grow = N - 1;
            unsigned srcb = ((unsigned)(l * 16)) ^ ((unsigned)(row & 7) << 4);
            load_lds_16(x + grow * D_IN + (srcb >> 2),
                        (char*)sxf[0] + (unsigned)(row * 1024 + l * 16));
        }
    }
    int bvalCur = -1;
    if (w == 0 && l < CHUNK) {
        long long bi = (long long)c0 * CHUNK + l;
        if (bi < N) bvalCur = batch[bi];
    }

    int par = 0;
    for (int t = c0; t < cEnd; ++t) {
        long long base = (long long)t * CHUNK;
        int chunkN = (int)min((long long)CHUNK, (long long)N - base);
        const float* P = sxf[par];

        __syncthreads();  // drains DMA(t); pool(t-1) reads of buf par^1 done

        // ---- issue DMA(t+1) into the other buffer + batch prefetch ----
        int bvalNext = -1;
        if (t + 1 < cEnd) {
            long long nbase = base + CHUNK;
#pragma unroll
            for (int k = 0; k < 4; ++k) {
                int row = k * 4 + w;
                long long grow = nbase + row;
                if (grow >= N) grow = N - 1;
                unsigned srcb = ((unsigned)(l * 16)) ^ ((unsigned)(row & 7) << 4);
                load_lds_16(x + grow * D_IN + (srcb >> 2),
                            (char*)sxf[par ^ 1] + (unsigned)(row * 1024 + l * 16));
            }
            if (w == 0 && l < CHUNK) {
                long long bi = nbase + l;
                if (bi < N) bvalNext = batch[bi];
            }
        }

        // ---- wave0: segment scan for chunk t ----
        if (w == 0) {
            int prev = __shfl_up(bvalCur, 1, 64);
            bool flag = (l < chunkN) && (l == 0 || bvalCur != prev);
            unsigned long long m = __ballot(flag);
            if (l == 0) {
                int ns = 0;
                while (m && ns < MAXSEG) {
                    seglist[par][ns] = __ffsll(m) - 1;
                    ns++;
                    m &= m - 1;
                }
                snseg[par] = ns;
                seglist[par][ns] = chunkN;
            }
        }

        // ---- MFMA: 1 row-tile (16 rows) x 2 n-tiles, A from LDS f32 ----
        f32x4 acc[2] = {};
#pragma unroll
        for (int ks = 0; ks < 8; ++ks) {
            int row = r16;
            unsigned swz = (unsigned)(row & 7) << 4;
            unsigned cb = (unsigned)(ks * 128 + kg * 32);
            f32x4 u0 = *(const f32x4*)((const char*)P + row * 1024 + (cb ^ swz));
            f32x4 u1 = *(const f32x4*)((const char*)P + row * 1024 + ((cb + 16) ^ swz));
            bf16x8 af;
#pragma unroll
            for (int i = 0; i < 4; ++i) {
                af[i] = (__bf16)u0[i];
                af[i + 4] = (__bf16)u1[i];
            }
            acc[0] = __builtin_amdgcn_mfma_f32_16x16x32_bf16(af, breg0[ks], acc[0], 0, 0, 0);
            acc[1] = __builtin_amdgcn_mfma_f32_16x16x32_bf16(af, breg1[ks], acc[1], 0, 0, 0);
        }
        // partial scores over this wave's 32 H-cols
#pragma unroll
        for (int reg = 0; reg < 4; ++reg) {
            float p = fmaxf(acc[0][reg] + b1v[0], 0.f) * w2v[0] +
                      fmaxf(acc[1][reg] + b1v[1], 0.f) * w2v[1];
            p += __shfl_xor(p, 1, 64);
            p += __shfl_xor(p, 2, 64);
            p += __shfl_xor(p, 4, 64);
            p += __shfl_xor(p, 8, 64);
            if (r16 == 0) pscore[w][kg * 4 + reg] = p;
        }

        bar_lds();  // pscore + seglist visible; DMA(t+1) stays in flight

        // ---- e per lane (rows are lanes 0..15) ----
        float e_l = 0.f;
        if (l < CHUNK) {
            float s = pscore[0][l] + pscore[1][l] + pscore[2][l] + pscore[3][l] + bb;
            e_l = (l < chunkN) ? __expf(s) : 0.f;
        }
        if (w == 0) {
            float z = e_l;
            z += __shfl_xor(z, 1, 64);
            z += __shfl_xor(z, 2, 64);
            z += __shfl_xor(z, 4, 64);
            z += __shfl_xor(z, 8, 64);
            if (l == 0) zacc += z;
        }

        int nseg = snseg[par];

        // ---- POOL (column-split, f32): rows rg+4j, j<4 ----
        if (nseg == 1 && chunkN == CHUNK) {
            // FAST PATH: single full segment -> zero masking
            f32x4 asum = {0.f, 0.f, 0.f, 0.f};
            f32x4 ssum = {0.f, 0.f, 0.f, 0.f};
            f32x4 mx = {-INFINITY, -INFINITY, -INFINITY, -INFINITY};
#pragma unroll
            for (int j = 0; j < 4; ++j) {
                int row = rg + 4 * j;
                float wj = __shfl(e_l, row, 64);
                unsigned addr = (unsigned)(row * 1024) +
                                (cbyte ^ ((unsigned)(row & 7) << 4));
                f32x4 v = *(const f32x4*)((const char*)P + addr);
#pragma unroll
                for (int c = 0; c < 4; ++c) {
                    asum[c] += v[c] * wj;
                    ssum[c] += v[c];
                    mx[c] = fmaxf(mx[c], v[c]);
                }
            }
#pragma unroll
            for (int c = 0; c < 4; ++c) {
                asum[c] += __shfl_xor(asum[c], 16, 64);
                asum[c] += __shfl_xor(asum[c], 32, 64);
                ssum[c] += __shfl_xor(ssum[c], 16, 64);
                ssum[c] += __shfl_xor(ssum[c], 32, 64);
                mx[c] = fmaxf(mx[c], __shfl_xor(mx[c], 16, 64));
                mx[c] = fmaxf(mx[c], __shfl_xor(mx[c], 32, 64));
            }
            if (rg == 0) {
                float* rb = recs + (size_t)(t * MAXSEG) * REC_F;
                int co = w * 64 + cg * 4;
                *(f32x4*)(rb + co) = asum;
                *(f32x4*)(rb + 256 + co) = ssum;
                *(f32x4*)(rb + 512 + co) = mx;
            }
        } else {
            for (int sg = 0; sg < nseg; ++sg) {
                int sStart = seglist[par][sg];
                int sEnd = seglist[par][sg + 1];
                f32x4 asum = {0.f, 0.f, 0.f, 0.f};
                f32x4 ssum = {0.f, 0.f, 0.f, 0.f};
                f32x4 mx = {-INFINITY, -INFINITY, -INFINITY, -INFINITY};
#pragma unroll
                for (int j = 0; j < 4; ++j) {
                    int row = rg + 4 * j;
                    float wj = __shfl(e_l, row, 64);
                    bool in = (row >= sStart) && (row < sEnd);
                    unsigned addr = (unsigned)(row * 1024) +
                                    (cbyte ^ ((unsigned)(row & 7) << 4));
                    f32x4 v = *(const f32x4*)((const char*)P + addr);
                    float wje = in ? wj : 0.f;
#pragma unroll
                    for (int c = 0; c < 4; ++c) {
                        asum[c] += v[c] * wje;
                        ssum[c] += in ? v[c] : 0.f;
                        mx[c] = fmaxf(mx[c], in ? v[c] : -INFINITY);
                    }
                }
#pragma unroll
                for (int c = 0; c < 4; ++c) {
                    asum[c] += __shfl_xor(asum[c], 16, 64);
                    asum[c] += __shfl_xor(asum[c], 32, 64);
                    ssum[c] += __shfl_xor(ssum[c], 16, 64);
                    ssum[c] += __shfl_xor(ssum[c], 32, 64);
                    mx[c] = fmaxf(mx[c], __shfl_xor(mx[c], 16, 64));
                    mx[c] = fmaxf(mx[c], __shfl_xor(mx[c], 32, 64));
                }
                if (rg == 0) {
                    float* rb = recs + (size_t)(t * MAXSEG + sg) * REC_F;
                    int co = w * 64 + cg * 4;
                    *(f32x4*)(rb + co) = asum;
                    *(f32x4*)(rb + 256 + co) = ssum;
                    *(f32x4*)(rb + 512 + co) = mx;
                }
            }
        }

        bvalCur = bvalNext;
        par ^= 1;
    }

    if (w == 0 && l == 0) zpart[blk] = zacc;
}

// ---------------------------------------------------------------------------
// combine: one block per graph. Z summed in-block over 1024 partials
// (deterministic fixed order). Seg index: 1 in the first chunk iff the chunk
// starts with an earlier graph; 0 in all later chunks.
// ---------------------------------------------------------------------------
__global__ __launch_bounds__(256) void combine_kernel(
    const float* __restrict__ recs, const int* __restrict__ bounds,
    const int* __restrict__ batch, const float* __restrict__ zpart, int nzp,
    float* __restrict__ out) {
    int g = blockIdx.x;
    int tid = threadIdx.x;

    __shared__ float szr[256];
    float z = 0.f;
    for (int i = tid; i < nzp; i += 256) z += zpart[i];
    szr[tid] = z;
    __syncthreads();
    for (int off = 128; off > 0; off >>= 1) {
        if (tid < off) szr[tid] += szr[tid + off];
        __syncthreads();
    }
    float invZ = 1.f / szr[0];

    int start = bounds[g];
    int end = bounds[g + 1];
    int cnt = end - start;

    float ew = 0.f, ss = 0.f, mxv = -INFINITY;
    if (cnt > 0) {
        int b0 = start / CHUNK, b1 = (end - 1) / CHUNK;
        int sg0 = (batch[(long long)b0 * CHUNK] == g) ? 0 : 1;
        for (int b = b0; b <= b1; ++b) {
            int sg = (b == b0) ? sg0 : 0;
            const float* rb = recs + (size_t)(b * MAXSEG + sg) * REC_F;
            ew += rb[tid];
            ss += rb[256 + tid];
            mxv = fmaxf(mxv, rb[512 + tid]);
        }
    }
    size_t ob = (size_t)g * (3 * D_IN);
    out[ob + tid] = ew * invZ;
    out[ob + D_IN + tid] = (cnt > 0) ? mxv : 0.f;
    out[ob + 2 * D_IN + tid] = ss / (float)max(cnt, 1);
}

// ---------------------------------------------------------------------------
extern "C" void kernel_launch(void* const* d_in, const int* in_sizes, int n_in,
                              void* d_out, int out_size, void* d_ws, size_t ws_size,
                              hipStream_t stream) {
    const float* x = (const float*)d_in[0];
    const float* W1 = (const float*)d_in[1];
    const float* b1 = (const float*)d_in[2];
    const float* W2 = (const float*)d_in[3];
    const float* b2 = (const float*)d_in[4];
    const int* batch = (const int*)d_in[5];
    int N = in_sizes[0] / D_IN;
    float* out = (float*)d_out;
    int NB = (N + CHUNK - 1) / CHUNK;
    int K = (NB + NPERS - 1) / NPERS;

    char* ws = (char*)d_ws;
    size_t off = 0;
    ushort* w1p = (ushort*)(ws + off);
    off += 8 * 8 * 64 * 8 * sizeof(ushort);  // 64 KB
    off = (off + 255) & ~(size_t)255;
    int* bounds = (int*)(ws + off);
    off += (NUM_GRAPHS + 1) * sizeof(int);
    off = (off + 255) & ~(size_t)255;
    float* recs = (float*)(ws + off);
    off += (size_t)NB * MAXSEG * REC_F * sizeof(float);  // ~192 MB
    off = (off + 255) & ~(size_t)255;
    float* zpart = (float*)(ws + off);
    off += (size_t)NPERS * sizeof(float);

    prep_kernel<<<21, 256, 0, stream>>>(W1, batch, N, w1p, bounds);
    fused_kernel<<<NPERS, 256, 0, stream>>>(x, w1p, b1, W2, b2, batch,
                                            recs, zpart, N, NB, K);
    combine_kernel<<<NUM_GRAPHS, 256, 0, stream>>>(recs, bounds, batch,
                                                   zpart, NPERS, out);
}

// Round 17
// 163.635 us; speedup vs baseline: 2.6913x; 2.6913x over previous
//
#include <hip/hip_runtime.h>
#include <cmath>

#define D_IN 256
#define H_DIM 128
#define NUM_GRAPHS 1024
#define CHUNK 32
#define MAXSEG 2
#define REC_F 768  // floats per record: ewsum[256], ssum[256], mx[256]

typedef __attribute__((ext_vector_type(8))) __bf16 bf16x8;
typedef __attribute__((ext_vector_type(4))) float f32x4;

// async global->LDS DMA, 16B per lane: dest = wave-uniform base + lane*16.
__device__ inline void load_lds_16(const void* g, void* l) {
    __builtin_amdgcn_global_load_lds(
        (const __attribute__((address_space(1))) void*)g,
        (__attribute__((address_space(3))) void*)l, 16, 0, 0);
}

__device__ inline int lower_bound_i(const int* __restrict__ arr, int n, int val) {
    int lo = 0, hi = n;
    while (lo < hi) {
        int mid = (lo + hi) >> 1;
        if (arr[mid] < val) lo = mid + 1; else hi = mid;
    }
    return lo;
}

// ---------------------------------------------------------------------------
// prep: blocks 0-15 pack W1 to MFMA B-frag order; blocks 16-20: per-graph
// bounds via binary search; blocks 21+: per-chunk segment metadata cmeta[b]
// (0 = whole chunk one graph; else index of the single boundary, valid since
// min graph size >> CHUNK).
// B-frag: lane l holds B[k][n], n = nt*16+(l&15), k = ks*32+(l>>4)*8+i.
// ---------------------------------------------------------------------------
__global__ __launch_bounds__(256) void prep_kernel(
    const float* __restrict__ W1, const int* __restrict__ batch, int N, int NB,
    ushort* __restrict__ packed, int* __restrict__ bounds,
    int* __restrict__ cmeta) {
    int b = blockIdx.x;
    if (b < 16) {
        int tid = b * 256 + threadIdx.x;
        int nt = tid >> 9;
        int ks = (tid >> 6) & 7;
        int l = tid & 63;
        int col = nt * 16 + (l & 15);
        int kbase = ks * 32 + ((l >> 4) & 3) * 8;
#pragma unroll
        for (int i = 0; i < 8; ++i) {
            float v = W1[(size_t)(kbase + i) * H_DIM + col];
            __bf16 h = (__bf16)v;
            packed[(size_t)tid * 8 + i] = __builtin_bit_cast(unsigned short, h);
        }
    } else if (b < 21) {
        int i = (b - 16) * 256 + threadIdx.x;
        if (i <= NUM_GRAPHS) bounds[i] = lower_bound_i(batch, N, i);
    } else {
        int c = (b - 21) * 256 + threadIdx.x;
        if (c < NB) {
            long long base = (long long)c * CHUNK;
            long long last = base + CHUNK - 1;
            if (last >= N) last = N - 1;
            int g0 = batch[base];
            int gend = batch[last];
            int p = 0;
            if (g0 != gend) {
                // smallest i in [1,31] with batch[base+i] != g0 (sorted)
                int lo = 1, hi = (int)(last - base);
                while (lo < hi) {
                    int mid = (lo + hi) >> 1;
                    if (batch[base + mid] != g0) hi = mid; else lo = mid + 1;
                }
                p = lo;
            }
            cmeta[c] = p;
        }
    }
}

// ---------------------------------------------------------------------------
// Fused kernel (R14 structure): one 32-row chunk per block (15626 blocks),
// 256 threads. x staged via global_load_lds DMA (f32, linear LDS, source-
// swizzled -> conflict-free reads). Score: nt-split, wave w owns H-cols
// [w*32,+32), W1 in regs. Pool: column-split, ONE record per (chunk,seg).
// Segment scan REPLACED by one uniform cmeta scalar (precomputed in prep).
// FAST PATH: single-full-segment chunks (~87%) pool with zero masking.
// ---------------------------------------------------------------------------
__global__ __launch_bounds__(256, 4) void fused_kernel(
    const float* __restrict__ x, const ushort* __restrict__ w1p,
    const float* __restrict__ b1, const float* __restrict__ W2,
    const float* __restrict__ b2, const int* __restrict__ cmeta,
    float* __restrict__ recs, float* __restrict__ zpart, int N) {
    int tid = threadIdx.x;
    int l = tid & 63;
    int w = tid >> 6;
    int r16 = l & 15;
    int kg = l >> 4;
    int blk = blockIdx.x;
    long long base = (long long)blk * CHUNK;
    int chunkN = (int)min((long long)CHUNK, (long long)N - base);

    __shared__ float sxf[CHUNK * D_IN];  // 32 KB f32 tile (source-swizzled)
    __shared__ float pscore[4][CHUNK];   // [wave][row]

    int meta = cmeta[blk];  // uniform scalar; replaces the whole segment scan

    // ---- 1. DMA x rows -> LDS. Per (k,w): one row; dest = row*1024 + l*16;
    //      source granule within row: (l*16) ^ ((row&7)<<4).
#pragma unroll
    for (int k = 0; k < 8; ++k) {
        int row = k * 4 + w;
        long long grow = base + row;
        if (grow >= N) grow = N - 1;
        unsigned srcb = ((unsigned)(l * 16)) ^ ((unsigned)(row & 7) << 4);
        const float* src = x + grow * D_IN + (srcb >> 2);
        char* dst = (char*)sxf + (unsigned)(row * 1024 + l * 16);
        load_lds_16(src, dst);
    }

    // ---- 2. per-wave W1 slice -> registers ----
    bf16x8 breg0[8], breg1[8];
#pragma unroll
    for (int ks = 0; ks < 8; ++ks) {
        breg0[ks] = *(const bf16x8*)(w1p + ((size_t)((w * 2) * 8 + ks) * 64 + l) * 8);
        breg1[ks] = *(const bf16x8*)(w1p + ((size_t)((w * 2 + 1) * 8 + ks) * 64 + l) * 8);
    }

    // ---- 3. epilogue constants ----
    float w2v[2], b1v[2];
#pragma unroll
    for (int q = 0; q < 2; ++q) {
        int c = (w * 2 + q) * 16 + r16;
        w2v[q] = W2[c];
        b1v[q] = b1[c];
    }
    float bb = b2[0];

    __syncthreads();  // barrier A: vmcnt(0) drains DMA

    // ---- 4. MFMA: read f32 A-frags from LDS, cvt, 2 n-tiles ----
    f32x4 acc[2][2] = {};
#pragma unroll
    for (int ks = 0; ks < 8; ++ks) {
#pragma unroll
        for (int mt = 0; mt < 2; ++mt) {
            int row = mt * 16 + r16;
            unsigned swz = (unsigned)(row & 7) << 4;
            unsigned cb = (unsigned)(ks * 128 + kg * 32);
            f32x4 u0 = *(const f32x4*)((const char*)sxf + row * 1024 + (cb ^ swz));
            f32x4 u1 = *(const f32x4*)((const char*)sxf + row * 1024 + ((cb + 16) ^ swz));
            bf16x8 af;
#pragma unroll
            for (int i = 0; i < 4; ++i) {
                af[i] = (__bf16)u0[i];
                af[i + 4] = (__bf16)u1[i];
            }
            acc[mt][0] = __builtin_amdgcn_mfma_f32_16x16x32_bf16(af, breg0[ks], acc[mt][0], 0, 0, 0);
            acc[mt][1] = __builtin_amdgcn_mfma_f32_16x16x32_bf16(af, breg1[ks], acc[mt][1], 0, 0, 0);
        }
    }
    // partial-score epilogue over this wave's 32 H-cols
#pragma unroll
    for (int mt = 0; mt < 2; ++mt) {
#pragma unroll
        for (int reg = 0; reg < 4; ++reg) {
            float p = fmaxf(acc[mt][0][reg] + b1v[0], 0.f) * w2v[0] +
                      fmaxf(acc[mt][1][reg] + b1v[1], 0.f) * w2v[1];
            p += __shfl_xor(p, 1, 64);
            p += __shfl_xor(p, 2, 64);
            p += __shfl_xor(p, 4, 64);
            p += __shfl_xor(p, 8, 64);
            if (r16 == 0) pscore[w][mt * 16 + kg * 4 + reg] = p;
        }
    }
    __syncthreads();  // barrier B: pscore complete

    // ---- 5. e per lane (rows are lanes 0..31) ----
    float e_l = 0.f;
    if (l < CHUNK) {
        float s = pscore[0][l] + pscore[1][l] + pscore[2][l] + pscore[3][l] + bb;
        e_l = (l < chunkN) ? __expf(s) : 0.f;
    }
    if (w == 0) {
        float z = e_l;
        z += __shfl_xor(z, 1, 64);
        z += __shfl_xor(z, 2, 64);
        z += __shfl_xor(z, 4, 64);
        z += __shfl_xor(z, 8, 64);
        z += __shfl_xor(z, 16, 64);
        z += __shfl_xor(z, 32, 64);
        if (l == 0) zpart[blk] = z;
    }

    // ---- 6. POOL (column-split, f32): wave w cols [w*64,+64);
    //      lane: cg=l&15 -> 4 cols, rg=l>>4 -> rows rg+4j.
    int cg = l & 15;
    int rg = l >> 4;
    unsigned cbyte = (unsigned)(w * 256 + cg * 16);

    if (meta == 0 && chunkN == CHUNK) {
        // ---- FAST PATH: single full segment -> zero masking ----
        f32x4 asum = {0.f, 0.f, 0.f, 0.f};
        f32x4 ssum = {0.f, 0.f, 0.f, 0.f};
        f32x4 mx = {-INFINITY, -INFINITY, -INFINITY, -INFINITY};
#pragma unroll
        for (int j = 0; j < 8; ++j) {
            int row = rg + 4 * j;
            float wj = __shfl(e_l, row, 64);
            unsigned addr = (unsigned)(row * 1024) +
                            (cbyte ^ ((unsigned)(row & 7) << 4));
            f32x4 v = *(const f32x4*)((const char*)sxf + addr);
#pragma unroll
            for (int c = 0; c < 4; ++c) {
                asum[c] += v[c] * wj;
                ssum[c] += v[c];
                mx[c] = fmaxf(mx[c], v[c]);
            }
        }
#pragma unroll
        for (int c = 0; c < 4; ++c) {
            asum[c] += __shfl_xor(asum[c], 16, 64);
            asum[c] += __shfl_xor(asum[c], 32, 64);
            ssum[c] += __shfl_xor(ssum[c], 16, 64);
            ssum[c] += __shfl_xor(ssum[c], 32, 64);
            mx[c] = fmaxf(mx[c], __shfl_xor(mx[c], 16, 64));
            mx[c] = fmaxf(mx[c], __shfl_xor(mx[c], 32, 64));
        }
        if (rg == 0) {
            float* rb = recs + (size_t)(blk * MAXSEG) * REC_F;
            int co = w * 64 + cg * 4;
            *(f32x4*)(rb + co) = asum;
            *(f32x4*)(rb + 256 + co) = ssum;
            *(f32x4*)(rb + 512 + co) = mx;
        }
    } else {
        // ---- SLOW PATH: <=2 segments, masked ----
        int nseg = meta ? 2 : 1;
        for (int sg = 0; sg < nseg; ++sg) {
            int sStart = (sg == 0) ? 0 : meta;
            int sEnd = (sg == nseg - 1) ? chunkN : meta;
            f32x4 asum = {0.f, 0.f, 0.f, 0.f};
            f32x4 ssum = {0.f, 0.f, 0.f, 0.f};
            f32x4 mx = {-INFINITY, -INFINITY, -INFINITY, -INFINITY};
#pragma unroll
            for (int j = 0; j < 8; ++j) {
                int row = rg + 4 * j;
                float wj = __shfl(e_l, row, 64);
                bool in = (row >= sStart) && (row < sEnd);
                unsigned addr = (unsigned)(row * 1024) +
                                (cbyte ^ ((unsigned)(row & 7) << 4));
                f32x4 v = *(const f32x4*)((const char*)sxf + addr);
                float wje = in ? wj : 0.f;
#pragma unroll
                for (int c = 0; c < 4; ++c) {
                    asum[c] += v[c] * wje;
                    ssum[c] += in ? v[c] : 0.f;
                    mx[c] = fmaxf(mx[c], in ? v[c] : -INFINITY);
                }
            }
#pragma unroll
            for (int c = 0; c < 4; ++c) {
                asum[c] += __shfl_xor(asum[c], 16, 64);
                asum[c] += __shfl_xor(asum[c], 32, 64);
                ssum[c] += __shfl_xor(ssum[c], 16, 64);
                ssum[c] += __shfl_xor(ssum[c], 32, 64);
                mx[c] = fmaxf(mx[c], __shfl_xor(mx[c], 16, 64));
                mx[c] = fmaxf(mx[c], __shfl_xor(mx[c], 32, 64));
            }
            if (rg == 0) {
                float* rb = recs + (size_t)(blk * MAXSEG + sg) * REC_F;
                int co = w * 64 + cg * 4;
                *(f32x4*)(rb + co) = asum;
                *(f32x4*)(rb + 256 + co) = ssum;
                *(f32x4*)(rb + 512 + co) = mx;
            }
        }
    }
}

// ---------------------------------------------------------------------------
// combine: one block per graph. Z summed in-block (deterministic order).
// Seg index of graph g in its first chunk: 0 if g starts the chunk
// (start % CHUNK == 0), else 1; 0 in all later chunks. No batch reads.
// ---------------------------------------------------------------------------
__global__ __launch_bounds__(256) void combine_kernel(
    const float* __restrict__ recs, const int* __restrict__ bounds,
    const float* __restrict__ zpart, int nzp, float* __restrict__ out) {
    int g = blockIdx.x;
    int tid = threadIdx.x;

    __shared__ float szr[256];
    float z = 0.f;
    for (int i = tid; i < nzp; i += 256) z += zpart[i];
    szr[tid] = z;
    __syncthreads();
    for (int off = 128; off > 0; off >>= 1) {
        if (tid < off) szr[tid] += szr[tid + off];
        __syncthreads();
    }
    float invZ = 1.f / szr[0];

    int start = bounds[g];
    int end = bounds[g + 1];
    int cnt = end - start;

    float ew = 0.f, ss = 0.f, mxv = -INFINITY;
    if (cnt > 0) {
        int b0 = start / CHUNK, b1 = (end - 1) / CHUNK;
        int sg0 = (start % CHUNK == 0) ? 0 : 1;
        for (int b = b0; b <= b1; ++b) {
            int sg = (b == b0) ? sg0 : 0;
            const float* rb = recs + (size_t)(b * MAXSEG + sg) * REC_F;
            ew += rb[tid];
            ss += rb[256 + tid];
            mxv = fmaxf(mxv, rb[512 + tid]);
        }
    }
    size_t ob = (size_t)g * (3 * D_IN);
    out[ob + tid] = ew * invZ;
    out[ob + D_IN + tid] = (cnt > 0) ? mxv : 0.f;
    out[ob + 2 * D_IN + tid] = ss / (float)max(cnt, 1);
}

// ---------------------------------------------------------------------------
extern "C" void kernel_launch(void* const* d_in, const int* in_sizes, int n_in,
                              void* d_out, int out_size, void* d_ws, size_t ws_size,
                              hipStream_t stream) {
    const float* x = (const float*)d_in[0];
    const float* W1 = (const float*)d_in[1];
    const float* b1 = (const float*)d_in[2];
    const float* W2 = (const float*)d_in[3];
    const float* b2 = (const float*)d_in[4];
    const int* batch = (const int*)d_in[5];
    int N = in_sizes[0] / D_IN;
    float* out = (float*)d_out;
    int NB = (N + CHUNK - 1) / CHUNK;

    char* ws = (char*)d_ws;
    size_t off = 0;
    ushort* w1p = (ushort*)(ws + off);
    off += 8 * 8 * 64 * 8 * sizeof(ushort);  // 64 KB
    off = (off + 255) & ~(size_t)255;
    int* bounds = (int*)(ws + off);
    off += (NUM_GRAPHS + 1) * sizeof(int);
    off = (off + 255) & ~(size_t)255;
    int* cmeta = (int*)(ws + off);
    off += (size_t)NB * sizeof(int);
    off = (off + 255) & ~(size_t)255;
    float* recs = (float*)(ws + off);
    off += (size_t)NB * MAXSEG * REC_F * sizeof(float);  // ~96 MB
    off = (off + 255) & ~(size_t)255;
    float* zpart = (float*)(ws + off);
    off += (size_t)NB * sizeof(float);

    int prepBlocks = 21 + (NB + 255) / 256;
    prep_kernel<<<prepBlocks, 256, 0, stream>>>(W1, batch, N, NB, w1p, bounds, cmeta);
    fused_kernel<<<NB, 256, 0, stream>>>(x, w1p, b1, W2, b2, cmeta,
                                         recs, zpart, N);
    combine_kernel<<<NUM_GRAPHS, 256, 0, stream>>>(recs, bounds, zpart, NB, out);
}